// Round 13
// baseline (524.874 us; speedup 1.0000x reference)
//
#include <hip/hip_runtime.h>
#include <hip/hip_bf16.h>
#include <math.h>

typedef __attribute__((ext_vector_type(8))) short short8v;
typedef __attribute__((ext_vector_type(4))) float float4v;

// ---------------- wave helpers (wave64) ----------------
__device__ __forceinline__ float wsum(float v) {
#pragma unroll
  for (int s = 32; s > 0; s >>= 1) v += __shfl_xor(v, s, 64);
  return v;
}
__device__ __forceinline__ unsigned bf16bits(float f) {  // round-to-nearest-even
  unsigned u = __float_as_uint(f);
  return (u + 0x7fffu + ((u >> 16) & 1u)) >> 16;
}

// ---------------- embed: hb[n][64] = bf16(leaky0.1(LN(x@W+b)*g+beta)) ------
__global__ void k_embed(const float* __restrict__ x, const float* __restrict__ w,
                        const float* __restrict__ b, const float* __restrict__ g,
                        const float* __restrict__ beta, short* __restrict__ hb, int n) {
  __shared__ float ws[16 * 64];
  for (int i = threadIdx.x; i < 16 * 64; i += blockDim.x) ws[i] = w[i];
  __syncthreads();
  int wid = (blockIdx.x * blockDim.x + threadIdx.x) >> 6;
  int lane = threadIdx.x & 63;
  if (wid >= n) return;
  const float* xr = x + (size_t)wid * 16;
  float acc = b[lane];
#pragma unroll
  for (int k = 0; k < 16; ++k) acc = fmaf(xr[k], ws[k * 64 + lane], acc);
  float mean = wsum(acc) * 0.015625f;
  float xc = acc - mean;
  float var = wsum(xc * xc) * 0.015625f;
  float y = xc * rsqrtf(var + 1e-5f) * g[lane] + beta[lane];
  y = (y >= 0.f) ? y : 0.1f * y;
  hb[(size_t)wid * 64 + lane] = (short)bf16bits(y);
}

// ---------------- CSR build (by dst), self-loops appended virtually --------
__global__ void k_deg(const int* __restrict__ ei, int E, int n, int* __restrict__ deg,
                      int* __restrict__ pos) {
  int i = blockIdx.x * blockDim.x + threadIdx.x;
  int tot = E + n;
  if (i >= tot) return;
  int d = (i < E) ? ei[E + i] : (i - E);
  pos[i] = atomicAdd(&deg[d], 1);
}

__global__ void k_scanA(const int* __restrict__ deg, int n, int* __restrict__ texcl,
                        int* __restrict__ bsum) {
  __shared__ int sh[256];
  int bid = blockIdx.x, tid = threadIdx.x;
  int base = bid * 2048 + tid * 8;
  int s = 0;
#pragma unroll
  for (int i = 0; i < 8; ++i) {
    int idx = base + i;
    s += (idx < n) ? deg[idx] : 0;
  }
  sh[tid] = s;
  __syncthreads();
  for (int st = 1; st < 256; st <<= 1) {
    int t = (tid >= st) ? sh[tid - st] : 0;
    __syncthreads();
    sh[tid] += t;
    __syncthreads();
  }
  texcl[bid * 256 + tid] = sh[tid] - s;
  if (tid == 255) bsum[bid] = sh[255];
}

__global__ void k_scanB(int* __restrict__ bsum, int nb) {
  __shared__ int sh[256];
  int tid = threadIdx.x;
  int v = (tid < nb) ? bsum[tid] : 0;
  sh[tid] = v;
  __syncthreads();
  for (int st = 1; st < 256; st <<= 1) {
    int t = (tid >= st) ? sh[tid - st] : 0;
    __syncthreads();
    sh[tid] += t;
    __syncthreads();
  }
  if (tid < nb) bsum[tid] = sh[tid] - v;  // exclusive
}

__global__ void k_scanC(const int* __restrict__ deg, int n, const int* __restrict__ texcl,
                        const int* __restrict__ bsum, int* __restrict__ off, int total) {
  int bid = blockIdx.x, tid = threadIdx.x;
  int run = bsum[bid] + texcl[bid * 256 + tid];
  int base = bid * 2048 + tid * 8;
#pragma unroll
  for (int i = 0; i < 8; ++i) {
    int idx = base + i;
    if (idx < n) {
      off[idx] = run;
      run += deg[idx];
    }
  }
  if (bid == 0 && tid == 0) off[n] = total;
}

__global__ void k_scatter(const int* __restrict__ ei, int E, int n,
                          const int* __restrict__ off, const int* __restrict__ pos,
                          int* __restrict__ csr) {
  int i = blockIdx.x * blockDim.x + threadIdx.x;
  int tot = E + n;
  if (i >= tot) return;
  int s, d;
  if (i < E) { s = ei[i]; d = ei[E + i]; } else { s = i - E; d = i - E; }
  csr[off[d] + pos[i]] = s;
}

// ---------------- hp = hb @ W via MFMA, fused attention logits -------------
__global__ __launch_bounds__(256) void k_hp(
    const short* __restrict__ hb, const float* __restrict__ W,
    const float* __restrict__ asrc, const float* __restrict__ adst,
    unsigned* __restrict__ hp2, float2* __restrict__ al_s, float2* __restrict__ al_d,
    int n) {
  __shared__ short wlds[16 * 64 * 8];  // 16 KB: [(kh*8+ct)*64 + lane]*8
  int tid = threadIdx.x;
  for (int idx = tid; idx < 1024; idx += 256) {
    int fr = idx >> 6;  // kh = fr>>3, ct = fr&7
    int ls = idx & 63;
    int kb = (fr >> 3) * 32 + (ls >> 4) * 8;
    int c = (fr & 7) * 16 + (ls & 15);
    short tmp[8];
#pragma unroll
    for (int j = 0; j < 8; ++j)
      tmp[j] = (short)bf16bits(W[(size_t)(kb + j) * 128 + c]);
    *reinterpret_cast<short8v*>(&wlds[idx * 8]) = *reinterpret_cast<const short8v*>(tmp);
  }
  __syncthreads();
  int lane = tid & 63;
  int nb = (blockIdx.x * 4 + (tid >> 6)) * 16;
  if (nb >= n) return;
  int col = lane & 15, kg = lane >> 4;
  int rowA = nb + col;
  if (rowA > n - 1) rowA = n - 1;  // clamp (safe duplicate read)
  const short8v* aptr = reinterpret_cast<const short8v*>(hb + (size_t)rowA * 64 + kg * 8);
  short8v af0 = aptr[0];
  short8v af1 = aptr[4];  // +32 elements (second K-half)
  float ps0[4] = {0, 0, 0, 0}, ps1[4] = {0, 0, 0, 0};
  float pd0[4] = {0, 0, 0, 0}, pd1[4] = {0, 0, 0, 0};
#pragma unroll
  for (int ctp = 0; ctp < 4; ++ctp) {
    const short8v* bp0 = reinterpret_cast<const short8v*>(&wlds[((0 * 8 + ctp) * 64 + lane) * 8]);
    const short8v* bp1 = reinterpret_cast<const short8v*>(&wlds[((1 * 8 + ctp) * 64 + lane) * 8]);
    float4v accA = {0.f, 0.f, 0.f, 0.f};
    accA = __builtin_amdgcn_mfma_f32_16x16x32_bf16(af0, *bp0, accA, 0, 0, 0);
    accA = __builtin_amdgcn_mfma_f32_16x16x32_bf16(af1, *bp1, accA, 0, 0, 0);
    const short8v* bq0 = reinterpret_cast<const short8v*>(&wlds[((0 * 8 + ctp + 4) * 64 + lane) * 8]);
    const short8v* bq1 = reinterpret_cast<const short8v*>(&wlds[((1 * 8 + ctp + 4) * 64 + lane) * 8]);
    float4v accB = {0.f, 0.f, 0.f, 0.f};
    accB = __builtin_amdgcn_mfma_f32_16x16x32_bf16(af0, *bq0, accB, 0, 0, 0);
    accB = __builtin_amdgcn_mfma_f32_16x16x32_bf16(af1, *bq1, accB, 0, 0, 0);
    int c = ctp * 16 + col;  // head-local column
    float a_s0 = asrc[c], a_s1 = asrc[64 + c];
    float a_d0 = adst[c], a_d1 = adst[64 + c];
#pragma unroll
    for (int r = 0; r < 4; ++r) {
      int node = nb + kg * 4 + r;
      unsigned pk = bf16bits(accA[r]) | (bf16bits(accB[r]) << 16);
      if (node < n) hp2[(size_t)node * 64 + c] = pk;
      ps0[r] = fmaf(accA[r], a_s0, ps0[r]);
      ps1[r] = fmaf(accB[r], a_s1, ps1[r]);
      pd0[r] = fmaf(accA[r], a_d0, pd0[r]);
      pd1[r] = fmaf(accB[r], a_d1, pd1[r]);
    }
  }
#pragma unroll
  for (int m = 1; m < 16; m <<= 1) {
#pragma unroll
    for (int r = 0; r < 4; ++r) {
      ps0[r] += __shfl_xor(ps0[r], m, 64);
      ps1[r] += __shfl_xor(ps1[r], m, 64);
      pd0[r] += __shfl_xor(pd0[r], m, 64);
      pd1[r] += __shfl_xor(pd1[r], m, 64);
    }
  }
  if (col == 0) {
#pragma unroll
    for (int r = 0; r < 4; ++r) {
      int node = nb + kg * 4 + r;
      if (node < n) {
        al_s[node] = make_float2(ps0[r], ps1[r]);
        al_d[node] = make_float2(pd0[r], pd1[r]);
      }
    }
  }
}

// ---------------- GAT aggregate + head-mean + bias + LN + leaky ------------
// Half-wave gather: lanes 0-31 serve even edge, 32-63 odd edge; each lane
// loads uint2 = 2 channels x {h0,h1} bf16. Edge records {s,w0,w1} staged in
// LDS by the lane-parallel weight pass; read back via ds_read_b128.
__global__ void k_gat(const unsigned* __restrict__ hp2, const float* __restrict__ al_s,
                      const float* __restrict__ al_d, const int* __restrict__ off,
                      const int* __restrict__ csr, const float* __restrict__ bias,
                      const float* __restrict__ g, const float* __restrict__ b,
                      short* __restrict__ hb, int n) {
  __shared__ uint4 recs[4][64];
  int gw = (blockIdx.x * blockDim.x + threadIdx.x) >> 6;
  if (gw >= n) return;
  int node = __builtin_amdgcn_readfirstlane(gw);
  int lane = threadIdx.x & 63;
  int wslot = (threadIdx.x >> 6) & 3;
  int hl = lane & 31;       // half-lane: channel pair index
  int halfSel = lane >> 5;  // 0 = even edge, 1 = odd edge
  const float2* al2 = (const float2*)al_s;
  float2 adv = ((const float2*)al_d)[node];
  int beg = off[node], end = off[node + 1];
  float a00 = 0.f, a01 = 0.f, a10 = 0.f, a11 = 0.f;  // [ch pair elem][head]
  float dnl0 = 0.f, dnl1 = 0.f;
  for (int cb = beg; cb < end; cb += 64) {
    int jj = cb + lane;
    int sv = 0;
    float w0v = 0.f, w1v = 0.f;
    if (jj < end) {
      sv = csr[jj];
      float2 e = al2[sv];
      float e0 = e.x + adv.x; e0 = (e0 >= 0.f) ? e0 : 0.2f * e0;
      float e1 = e.y + adv.y; e1 = (e1 >= 0.f) ? e1 : 0.2f * e1;
      w0v = __expf(e0);
      w1v = __expf(e1);
    }
    dnl0 += w0v; dnl1 += w1v;
    recs[wslot][lane] =
        make_uint4((unsigned)sv, __float_as_uint(w0v), __float_as_uint(w1v), 0u);
    const uint4* rb = &recs[wslot][0];
    int cnt = min(64, end - cb);
    int t = 0;
    for (; t + 4 <= cnt; t += 4) {  // 2 pairs per iter: 2 loads in flight
      uint4 rA = rb[t + halfSel];
      uint4 rB = rb[t + 2 + halfSel];
      uint2 uA = *reinterpret_cast<const uint2*>(hp2 + (size_t)rA.x * 64 + 2 * hl);
      uint2 uB = *reinterpret_cast<const uint2*>(hp2 + (size_t)rB.x * 64 + 2 * hl);
      float wA0 = __uint_as_float(rA.y), wA1 = __uint_as_float(rA.z);
      float wB0 = __uint_as_float(rB.y), wB1 = __uint_as_float(rB.z);
      a00 = fmaf(wA0, __uint_as_float(uA.x << 16), a00);
      a01 = fmaf(wA1, __uint_as_float(uA.x & 0xffff0000u), a01);
      a10 = fmaf(wA0, __uint_as_float(uA.y << 16), a10);
      a11 = fmaf(wA1, __uint_as_float(uA.y & 0xffff0000u), a11);
      a00 = fmaf(wB0, __uint_as_float(uB.x << 16), a00);
      a01 = fmaf(wB1, __uint_as_float(uB.x & 0xffff0000u), a01);
      a10 = fmaf(wB0, __uint_as_float(uB.y << 16), a10);
      a11 = fmaf(wB1, __uint_as_float(uB.y & 0xffff0000u), a11);
    }
    for (; t < cnt; t += 2) {  // tail pair (odd record has w=0 if t+1==cnt)
      uint4 r = rb[t + halfSel];
      uint2 u = *reinterpret_cast<const uint2*>(hp2 + (size_t)r.x * 64 + 2 * hl);
      float w0 = __uint_as_float(r.y), w1 = __uint_as_float(r.z);
      a00 = fmaf(w0, __uint_as_float(u.x << 16), a00);
      a01 = fmaf(w1, __uint_as_float(u.x & 0xffff0000u), a01);
      a10 = fmaf(w0, __uint_as_float(u.y << 16), a10);
      a11 = fmaf(w1, __uint_as_float(u.y & 0xffff0000u), a11);
    }
  }
  // merge even/odd edge halves (lane l and l^32 hold same channel pair)
  a00 += __shfl_xor(a00, 32, 64);
  a01 += __shfl_xor(a01, 32, 64);
  a10 += __shfl_xor(a10, 32, 64);
  a11 += __shfl_xor(a11, 32, 64);
  // redistribute: lane l wants channel l = pair (l>>1), element (l&1)
  int src = lane >> 1;
  float e0h0 = __shfl(a00, src, 64), e1h0 = __shfl(a10, src, 64);
  float e0h1 = __shfl(a01, src, 64), e1h1 = __shfl(a11, src, 64);
  float acc0 = (lane & 1) ? e1h0 : e0h0;
  float acc1 = (lane & 1) ? e1h1 : e0h1;
  float dn0 = wsum(dnl0), dn1 = wsum(dnl1);
  float oc = 0.5f * (acc0 / (dn0 + 1e-16f) + acc1 / (dn1 + 1e-16f)) + bias[lane];
  float mean = wsum(oc) * 0.015625f;
  float xc = oc - mean;
  float var = wsum(xc * xc) * 0.015625f;
  float y = xc * rsqrtf(var + 1e-5f) * g[lane] + b[lane];
  y = (y >= 0.f) ? y : 0.1f * y;
  hb[(size_t)node * 64 + lane] = (short)bf16bits(y);
}

// ---------------- global mean pool (column sums, bf16 input) ---------------
__global__ void k_pool(const short* __restrict__ hb, float* __restrict__ gsum, int n) {
  __shared__ float sh[256];
  int col = threadIdx.x & 63;
  int rw = threadIdx.x >> 6;
  float acc = 0.f;
  for (long r = (long)blockIdx.x * 4 + rw; r < n; r += (long)gridDim.x * 4) {
    unsigned u = (unsigned)(unsigned short)hb[r * 64 + col];
    acc += __uint_as_float(u << 16);
  }
  sh[threadIdx.x] = acc;
  __syncthreads();
  if (threadIdx.x < 64) {
    float s = sh[threadIdx.x] + sh[64 + threadIdx.x] + sh[128 + threadIdx.x] +
              sh[192 + threadIdx.x];
    atomicAdd(&gsum[col], s);
  }
}

// ---------------- head: fc1 -> LN -> leaky -> fc2 -> sigmoid ---------------
__global__ void k_head(const float* __restrict__ gsum, const float* __restrict__ fc1w,
                       const float* __restrict__ fc1b, const float* __restrict__ fng,
                       const float* __restrict__ fnb, const float* __restrict__ fc2w,
                       const float* __restrict__ fc2b, float* __restrict__ out,
                       float invN) {
  __shared__ float t[64];
  __shared__ float gl[64];
  int tid = threadIdx.x;
  if (tid < 64) gl[tid] = gsum[tid] * invN;
  __syncthreads();
  if (tid < 64) {  // wave 0 only
    float z = fc1b[tid];
    for (int k = 0; k < 64; ++k) z = fmaf(gl[k], fc1w[k * 64 + tid], z);
    float mean = wsum(z) * 0.015625f;
    float xc = z - mean;
    float var = wsum(xc * xc) * 0.015625f;
    float y = xc * rsqrtf(var + 1e-5f) * fng[tid] + fnb[tid];
    t[tid] = (y >= 0.f) ? y : 0.1f * y;
  }
  __syncthreads();
  if (tid < 200) {
    float o = fc2b[tid];
    for (int k = 0; k < 64; ++k) o = fmaf(t[k], fc2w[k * 200 + tid], o);
    out[tid] = 1.f / (1.f + expf(-o));
  }
}

// ---------------------------------------------------------------------------
extern "C" void kernel_launch(void* const* d_in, const int* in_sizes, int n_in,
                              void* d_out, int out_size, void* d_ws, size_t ws_size,
                              hipStream_t stream) {
  const float* x      = (const float*)d_in[0];
  const int*   ei     = (const int*)d_in[1];
  const float* emb_w  = (const float*)d_in[2];
  const float* emb_b  = (const float*)d_in[3];
  const float* emb_g  = (const float*)d_in[4];
  const float* emb_be = (const float*)d_in[5];
  const float* lin_w  = (const float*)d_in[6];
  const float* att_s  = (const float*)d_in[7];
  const float* att_d  = (const float*)d_in[8];
  const float* conv_b = (const float*)d_in[9];
  const float* ln_g   = (const float*)d_in[10];
  const float* ln_b   = (const float*)d_in[11];
  const float* fc1_w  = (const float*)d_in[12];
  const float* fc1_b  = (const float*)d_in[13];
  const float* fcn_g  = (const float*)d_in[14];
  const float* fcn_b  = (const float*)d_in[15];
  const float* fc2_w  = (const float*)d_in[16];
  const float* fc2_b  = (const float*)d_in[17];
  float* out = (float*)d_out;

  int N = in_sizes[0] / 16;
  int E = in_sizes[1] / 2;
  int tot = E + N;
  int nb_scan = (N + 2047) / 2048;  // 49 for N=100k (<=256 required)

  char* p = (char*)d_ws;
  auto alloc = [&](size_t bytes) {
    char* r = p;
    p += (bytes + 255) & ~(size_t)255;
    return r;
  };
  short*    hb    = (short*)alloc((size_t)N * 64 * 2);
  unsigned* hp2   = (unsigned*)alloc((size_t)N * 64 * 4);
  float2*   al_s  = (float2*)alloc((size_t)N * 8);
  float2*   al_d  = (float2*)alloc((size_t)N * 8);
  int*      deg   = (int*)alloc((size_t)N * 4);
  int*      off   = (int*)alloc((size_t)(N + 1) * 4);
  int*      pos   = (int*)alloc((size_t)tot * 4);
  int*      csr   = (int*)alloc((size_t)tot * 4);
  float*    gsum  = (float*)alloc(64 * 4);
  int*      texcl = (int*)alloc((size_t)nb_scan * 256 * 4);
  int*      bsum  = (int*)alloc((size_t)nb_scan * 4);

  hipMemsetAsync(deg, 0, (size_t)N * 4, stream);
  hipMemsetAsync(gsum, 0, 64 * 4, stream);

  int eb = (tot + 255) / 256;
  k_deg<<<eb, 256, 0, stream>>>(ei, E, N, deg, pos);
  k_scanA<<<nb_scan, 256, 0, stream>>>(deg, N, texcl, bsum);
  k_scanB<<<1, 256, 0, stream>>>(bsum, nb_scan);
  k_scanC<<<nb_scan, 256, 0, stream>>>(deg, N, texcl, bsum, off, tot);
  k_scatter<<<eb, 256, 0, stream>>>(ei, E, N, off, pos, csr);

  int nbe = (N + 3) / 4;  // one wave per node, 4 waves/block
  k_embed<<<nbe, 256, 0, stream>>>(x, emb_w, emb_b, emb_g, emb_be, hb, N);

  int nbh = (N + 63) / 64;  // 16 nodes/wave, 64 nodes/block (MFMA)
  for (int l = 0; l < 3; ++l) {
    k_hp<<<nbh, 256, 0, stream>>>(hb, lin_w + (size_t)l * 64 * 128, att_s + l * 128,
                                  att_d + l * 128, hp2, al_s, al_d, N);
    k_gat<<<nbe, 256, 0, stream>>>(hp2, (const float*)al_s, (const float*)al_d, off,
                                   csr, conv_b + l * 64, ln_g + l * 64, ln_b + l * 64,
                                   hb, N);
  }

  k_pool<<<1024, 256, 0, stream>>>(hb, gsum, N);
  k_head<<<1, 256, 0, stream>>>(gsum, fc1_w, fc1_b, fcn_g, fcn_b, fc2_w, fc2_b, out,
                                1.0f / (float)N);
}

// Round 15
// 523.085 us; speedup vs baseline: 1.0034x; 1.0034x over previous
//
#include <hip/hip_runtime.h>
#include <hip/hip_bf16.h>
#include <math.h>

typedef __attribute__((ext_vector_type(8))) short short8v;
typedef __attribute__((ext_vector_type(4))) float float4v;

// ---------------- wave helpers (wave64) ----------------
__device__ __forceinline__ float wsum(float v) {
#pragma unroll
  for (int s = 32; s > 0; s >>= 1) v += __shfl_xor(v, s, 64);
  return v;
}
__device__ __forceinline__ float bcast(float v, int l) {
  return __int_as_float(__builtin_amdgcn_readlane(__float_as_int(v), l));
}
__device__ __forceinline__ int bcasti(int v, int l) {
  return __builtin_amdgcn_readlane(v, l);
}
__device__ __forceinline__ unsigned bf16bits(float f) {  // round-to-nearest-even
  unsigned u = __float_as_uint(f);
  return (u + 0x7fffu + ((u >> 16) & 1u)) >> 16;
}

// ---------------- embed: hb[n][64] = bf16(leaky0.1(LN(x@W+b)*g+beta)) ------
__global__ void k_embed(const float* __restrict__ x, const float* __restrict__ w,
                        const float* __restrict__ b, const float* __restrict__ g,
                        const float* __restrict__ beta, short* __restrict__ hb, int n) {
  __shared__ float ws[16 * 64];
  for (int i = threadIdx.x; i < 16 * 64; i += blockDim.x) ws[i] = w[i];
  __syncthreads();
  int wid = (blockIdx.x * blockDim.x + threadIdx.x) >> 6;
  int lane = threadIdx.x & 63;
  if (wid >= n) return;
  const float* xr = x + (size_t)wid * 16;
  float acc = b[lane];
#pragma unroll
  for (int k = 0; k < 16; ++k) acc = fmaf(xr[k], ws[k * 64 + lane], acc);
  float mean = wsum(acc) * 0.015625f;
  float xc = acc - mean;
  float var = wsum(xc * xc) * 0.015625f;
  float y = xc * rsqrtf(var + 1e-5f) * g[lane] + beta[lane];
  y = (y >= 0.f) ? y : 0.1f * y;
  hb[(size_t)wid * 64 + lane] = (short)bf16bits(y);
}

// ---------------- CSR build (by dst), self-loops appended virtually --------
__global__ void k_deg(const int* __restrict__ ei, int E, int n, int* __restrict__ deg,
                      int* __restrict__ pos) {
  int i = blockIdx.x * blockDim.x + threadIdx.x;
  int tot = E + n;
  if (i >= tot) return;
  int d = (i < E) ? ei[E + i] : (i - E);
  pos[i] = atomicAdd(&deg[d], 1);
}

__global__ void k_scanA(const int* __restrict__ deg, int n, int* __restrict__ texcl,
                        int* __restrict__ bsum) {
  __shared__ int sh[256];
  int bid = blockIdx.x, tid = threadIdx.x;
  int base = bid * 2048 + tid * 8;
  int s = 0;
#pragma unroll
  for (int i = 0; i < 8; ++i) {
    int idx = base + i;
    s += (idx < n) ? deg[idx] : 0;
  }
  sh[tid] = s;
  __syncthreads();
  for (int st = 1; st < 256; st <<= 1) {
    int t = (tid >= st) ? sh[tid - st] : 0;
    __syncthreads();
    sh[tid] += t;
    __syncthreads();
  }
  texcl[bid * 256 + tid] = sh[tid] - s;
  if (tid == 255) bsum[bid] = sh[255];
}

__global__ void k_scanB(int* __restrict__ bsum, int nb) {
  __shared__ int sh[256];
  int tid = threadIdx.x;
  int v = (tid < nb) ? bsum[tid] : 0;
  sh[tid] = v;
  __syncthreads();
  for (int st = 1; st < 256; st <<= 1) {
    int t = (tid >= st) ? sh[tid - st] : 0;
    __syncthreads();
    sh[tid] += t;
    __syncthreads();
  }
  if (tid < nb) bsum[tid] = sh[tid] - v;  // exclusive
}

__global__ void k_scanC(const int* __restrict__ deg, int n, const int* __restrict__ texcl,
                        const int* __restrict__ bsum, int* __restrict__ off, int total) {
  int bid = blockIdx.x, tid = threadIdx.x;
  int run = bsum[bid] + texcl[bid * 256 + tid];
  int base = bid * 2048 + tid * 8;
#pragma unroll
  for (int i = 0; i < 8; ++i) {
    int idx = base + i;
    if (idx < n) {
      off[idx] = run;
      run += deg[idx];
    }
  }
  if (bid == 0 && tid == 0) off[n] = total;
}

__global__ void k_scatter(const int* __restrict__ ei, int E, int n,
                          const int* __restrict__ off, const int* __restrict__ pos,
                          int* __restrict__ csr) {
  int i = blockIdx.x * blockDim.x + threadIdx.x;
  int tot = E + n;
  if (i >= tot) return;
  int s, d;
  if (i < E) { s = ei[i]; d = ei[E + i]; } else { s = i - E; d = i - E; }
  csr[off[d] + pos[i]] = s;
}

// ---------------- hp = hb @ W via MFMA, fused attention logits -------------
// Grid-strided: W staged to LDS once per block, then loop over node tiles.
__global__ __launch_bounds__(256) void k_hp(
    const short* __restrict__ hb, const float* __restrict__ W,
    const float* __restrict__ asrc, const float* __restrict__ adst,
    unsigned* __restrict__ hp2, float2* __restrict__ al_s, float2* __restrict__ al_d,
    int n, int ntiles) {
  __shared__ short wlds[16 * 64 * 8];  // 16 KB: [(kh*8+ct)*64 + lane]*8
  int tid = threadIdx.x;
  for (int idx = tid; idx < 1024; idx += 256) {
    int fr = idx >> 6;  // kh = fr>>3, ct = fr&7
    int ls = idx & 63;
    int kb = (fr >> 3) * 32 + (ls >> 4) * 8;
    int c = (fr & 7) * 16 + (ls & 15);
    short tmp[8];
#pragma unroll
    for (int j = 0; j < 8; ++j)
      tmp[j] = (short)bf16bits(W[(size_t)(kb + j) * 128 + c]);
    *reinterpret_cast<short8v*>(&wlds[idx * 8]) = *reinterpret_cast<const short8v*>(tmp);
  }
  __syncthreads();
  int lane = tid & 63;
  int warp = tid >> 6;
  int col = lane & 15, kg = lane >> 4;
  for (int tile = blockIdx.x; tile < ntiles; tile += gridDim.x) {
    int nb = (tile * 4 + warp) * 16;
    if (nb >= n) continue;
    int rowA = nb + col;
    if (rowA > n - 1) rowA = n - 1;  // clamp (safe duplicate read)
    const short8v* aptr =
        reinterpret_cast<const short8v*>(hb + (size_t)rowA * 64 + kg * 8);
    short8v af0 = aptr[0];
    short8v af1 = aptr[4];  // +32 elements (second K-half)
    float ps0[4] = {0, 0, 0, 0}, ps1[4] = {0, 0, 0, 0};
    float pd0[4] = {0, 0, 0, 0}, pd1[4] = {0, 0, 0, 0};
#pragma unroll
    for (int ctp = 0; ctp < 4; ++ctp) {
      const short8v* bp0 =
          reinterpret_cast<const short8v*>(&wlds[((0 * 8 + ctp) * 64 + lane) * 8]);
      const short8v* bp1 =
          reinterpret_cast<const short8v*>(&wlds[((1 * 8 + ctp) * 64 + lane) * 8]);
      float4v accA = {0.f, 0.f, 0.f, 0.f};
      accA = __builtin_amdgcn_mfma_f32_16x16x32_bf16(af0, *bp0, accA, 0, 0, 0);
      accA = __builtin_amdgcn_mfma_f32_16x16x32_bf16(af1, *bp1, accA, 0, 0, 0);
      const short8v* bq0 =
          reinterpret_cast<const short8v*>(&wlds[((0 * 8 + ctp + 4) * 64 + lane) * 8]);
      const short8v* bq1 =
          reinterpret_cast<const short8v*>(&wlds[((1 * 8 + ctp + 4) * 64 + lane) * 8]);
      float4v accB = {0.f, 0.f, 0.f, 0.f};
      accB = __builtin_amdgcn_mfma_f32_16x16x32_bf16(af0, *bq0, accB, 0, 0, 0);
      accB = __builtin_amdgcn_mfma_f32_16x16x32_bf16(af1, *bq1, accB, 0, 0, 0);
      int c = ctp * 16 + col;  // head-local column
      float a_s0 = asrc[c], a_s1 = asrc[64 + c];
      float a_d0 = adst[c], a_d1 = adst[64 + c];
#pragma unroll
      for (int r = 0; r < 4; ++r) {
        int node = nb + kg * 4 + r;
        unsigned pk = bf16bits(accA[r]) | (bf16bits(accB[r]) << 16);
        if (node < n) hp2[(size_t)node * 64 + c] = pk;
        ps0[r] = fmaf(accA[r], a_s0, ps0[r]);
        ps1[r] = fmaf(accB[r], a_s1, ps1[r]);
        pd0[r] = fmaf(accA[r], a_d0, pd0[r]);
        pd1[r] = fmaf(accB[r], a_d1, pd1[r]);
      }
    }
#pragma unroll
    for (int m = 1; m < 16; m <<= 1) {
#pragma unroll
      for (int r = 0; r < 4; ++r) {
        ps0[r] += __shfl_xor(ps0[r], m, 64);
        ps1[r] += __shfl_xor(ps1[r], m, 64);
        pd0[r] += __shfl_xor(pd0[r], m, 64);
        pd1[r] += __shfl_xor(pd1[r], m, 64);
      }
    }
    if (col == 0) {
#pragma unroll
      for (int r = 0; r < 4; ++r) {
        int node = nb + kg * 4 + r;
        if (node < n) {
          al_s[node] = make_float2(ps0[r], ps1[r]);
          al_d[node] = make_float2(pd0[r], pd1[r]);
        }
      }
    }
  }
}

// ---------------- GAT aggregate + head-mean + bias + LN + leaky ------------
// Latency-bound gather: 8 independent hp2 loads in flight per wave (R12
// structure, unroll 4->8). Weights lane-parallel (one exp/edge), broadcast
// via readlane (SGPR), hp gathered as bf16x2 (4B/lane, 256B/edge).
__global__ void k_gat(const unsigned* __restrict__ hp2, const float* __restrict__ al_s,
                      const float* __restrict__ al_d, const int* __restrict__ off,
                      const int* __restrict__ csr, const float* __restrict__ bias,
                      const float* __restrict__ g, const float* __restrict__ b,
                      short* __restrict__ hb, int n) {
  int gw = (blockIdx.x * blockDim.x + threadIdx.x) >> 6;
  if (gw >= n) return;
  int node = __builtin_amdgcn_readfirstlane(gw);
  int lane = threadIdx.x & 63;
  const float2* al2 = (const float2*)al_s;
  float2 adv = ((const float2*)al_d)[node];
  int beg = off[node], end = off[node + 1];
  float acc0 = 0.f, acc1 = 0.f, dnl0 = 0.f, dnl1 = 0.f;
  for (int cb = beg; cb < end; cb += 64) {
    int jj = cb + lane;
    int sv = 0;
    float w0v = 0.f, w1v = 0.f;
    if (jj < end) {
      sv = csr[jj];
      float2 e = al2[sv];
      float e0 = e.x + adv.x; e0 = (e0 >= 0.f) ? e0 : 0.2f * e0;
      float e1 = e.y + adv.y; e1 = (e1 >= 0.f) ? e1 : 0.2f * e1;
      w0v = __expf(e0);
      w1v = __expf(e1);
    }
    dnl0 += w0v; dnl1 += w1v;
    int cnt = min(64, end - cb);
    int t = 0;
    for (; t + 8 <= cnt; t += 8) {  // 8 gathers in flight
      unsigned u[8];
      float w0[8], w1[8];
#pragma unroll
      for (int i = 0; i < 8; ++i) {
        int s = bcasti(sv, t + i);
        w0[i] = bcast(w0v, t + i);
        w1[i] = bcast(w1v, t + i);
        u[i] = hp2[(size_t)s * 64 + lane];
      }
#pragma unroll
      for (int i = 0; i < 8; ++i) {
        acc0 = fmaf(w0[i], __uint_as_float(u[i] << 16), acc0);
        acc1 = fmaf(w1[i], __uint_as_float(u[i] & 0xffff0000u), acc1);
      }
    }
    for (; t < cnt; ++t) {
      int s = bcasti(sv, t);
      float w0 = bcast(w0v, t), w1 = bcast(w1v, t);
      unsigned u = hp2[(size_t)s * 64 + lane];
      acc0 = fmaf(w0, __uint_as_float(u << 16), acc0);
      acc1 = fmaf(w1, __uint_as_float(u & 0xffff0000u), acc1);
    }
  }
  float dn0 = wsum(dnl0), dn1 = wsum(dnl1);
  float oc = 0.5f * (acc0 / (dn0 + 1e-16f) + acc1 / (dn1 + 1e-16f)) + bias[lane];
  float mean = wsum(oc) * 0.015625f;
  float xc = oc - mean;
  float var = wsum(xc * xc) * 0.015625f;
  float y = xc * rsqrtf(var + 1e-5f) * g[lane] + b[lane];
  y = (y >= 0.f) ? y : 0.1f * y;
  hb[(size_t)node * 64 + lane] = (short)bf16bits(y);
}

// ---------------- global mean pool (column sums, bf16 input) ---------------
__global__ void k_pool(const short* __restrict__ hb, float* __restrict__ gsum, int n) {
  __shared__ float sh[256];
  int col = threadIdx.x & 63;
  int rw = threadIdx.x >> 6;
  float acc = 0.f;
  for (long r = (long)blockIdx.x * 4 + rw; r < n; r += (long)gridDim.x * 4) {
    unsigned u = (unsigned)(unsigned short)hb[r * 64 + col];
    acc += __uint_as_float(u << 16);
  }
  sh[threadIdx.x] = acc;
  __syncthreads();
  if (threadIdx.x < 64) {
    float s = sh[threadIdx.x] + sh[64 + threadIdx.x] + sh[128 + threadIdx.x] +
              sh[192 + threadIdx.x];
    atomicAdd(&gsum[col], s);
  }
}

// ---------------- head: fc1 -> LN -> leaky -> fc2 -> sigmoid ---------------
__global__ void k_head(const float* __restrict__ gsum, const float* __restrict__ fc1w,
                       const float* __restrict__ fc1b, const float* __restrict__ fng,
                       const float* __restrict__ fnb, const float* __restrict__ fc2w,
                       const float* __restrict__ fc2b, float* __restrict__ out,
                       float invN) {
  __shared__ float t[64];
  __shared__ float gl[64];
  int tid = threadIdx.x;
  if (tid < 64) gl[tid] = gsum[tid] * invN;
  __syncthreads();
  if (tid < 64) {  // wave 0 only
    float z = fc1b[tid];
    for (int k = 0; k < 64; ++k) z = fmaf(gl[k], fc1w[k * 64 + tid], z);
    float mean = wsum(z) * 0.015625f;
    float xc = z - mean;
    float var = wsum(xc * xc) * 0.015625f;
    float y = xc * rsqrtf(var + 1e-5f) * fng[tid] + fnb[tid];
    t[tid] = (y >= 0.f) ? y : 0.1f * y;
  }
  __syncthreads();
  if (tid < 200) {
    float o = fc2b[tid];
    for (int k = 0; k < 64; ++k) o = fmaf(t[k], fc2w[k * 200 + tid], o);
    out[tid] = 1.f / (1.f + expf(-o));
  }
}

// ---------------------------------------------------------------------------
extern "C" void kernel_launch(void* const* d_in, const int* in_sizes, int n_in,
                              void* d_out, int out_size, void* d_ws, size_t ws_size,
                              hipStream_t stream) {
  const float* x      = (const float*)d_in[0];
  const int*   ei     = (const int*)d_in[1];
  const float* emb_w  = (const float*)d_in[2];
  const float* emb_b  = (const float*)d_in[3];
  const float* emb_g  = (const float*)d_in[4];
  const float* emb_be = (const float*)d_in[5];
  const float* lin_w  = (const float*)d_in[6];
  const float* att_s  = (const float*)d_in[7];
  const float* att_d  = (const float*)d_in[8];
  const float* conv_b = (const float*)d_in[9];
  const float* ln_g   = (const float*)d_in[10];
  const float* ln_b   = (const float*)d_in[11];
  const float* fc1_w  = (const float*)d_in[12];
  const float* fc1_b  = (const float*)d_in[13];
  const float* fcn_g  = (const float*)d_in[14];
  const float* fcn_b  = (const float*)d_in[15];
  const float* fc2_w  = (const float*)d_in[16];
  const float* fc2_b  = (const float*)d_in[17];
  float* out = (float*)d_out;

  int N = in_sizes[0] / 16;
  int E = in_sizes[1] / 2;
  int tot = E + N;
  int nb_scan = (N + 2047) / 2048;  // 49 for N=100k (<=256 required)

  char* p = (char*)d_ws;
  auto alloc = [&](size_t bytes) {
    char* r = p;
    p += (bytes + 255) & ~(size_t)255;
    return r;
  };
  short*    hb    = (short*)alloc((size_t)N * 64 * 2);
  unsigned* hp2   = (unsigned*)alloc((size_t)N * 64 * 4);
  float2*   al_s  = (float2*)alloc((size_t)N * 8);
  float2*   al_d  = (float2*)alloc((size_t)N * 8);
  int*      deg   = (int*)alloc((size_t)N * 4);
  int*      off   = (int*)alloc((size_t)(N + 1) * 4);
  int*      pos   = (int*)alloc((size_t)tot * 4);
  int*      csr   = (int*)alloc((size_t)tot * 4);
  float*    gsum  = (float*)alloc(64 * 4);
  int*      texcl = (int*)alloc((size_t)nb_scan * 256 * 4);
  int*      bsum  = (int*)alloc((size_t)nb_scan * 4);

  hipMemsetAsync(deg, 0, (size_t)N * 4, stream);
  hipMemsetAsync(gsum, 0, 64 * 4, stream);

  int eb = (tot + 255) / 256;
  k_deg<<<eb, 256, 0, stream>>>(ei, E, N, deg, pos);
  k_scanA<<<nb_scan, 256, 0, stream>>>(deg, N, texcl, bsum);
  k_scanB<<<1, 256, 0, stream>>>(bsum, nb_scan);
  k_scanC<<<nb_scan, 256, 0, stream>>>(deg, N, texcl, bsum, off, tot);
  k_scatter<<<eb, 256, 0, stream>>>(ei, E, N, off, pos, csr);

  int nbe = (N + 3) / 4;  // one wave per node, 4 waves/block
  k_embed<<<nbe, 256, 0, stream>>>(x, emb_w, emb_b, emb_g, emb_be, hb, N);

  int ntiles = (N + 63) / 64;                 // 64 nodes per tile
  int nbh = ntiles < 512 ? ntiles : 512;      // grid-stride, W staged once/block
  for (int l = 0; l < 3; ++l) {
    k_hp<<<nbh, 256, 0, stream>>>(hb, lin_w + (size_t)l * 64 * 128, att_s + l * 128,
                                  att_d + l * 128, hp2, al_s, al_d, N, ntiles);
    k_gat<<<nbe, 256, 0, stream>>>(hp2, (const float*)al_s, (const float*)al_d, off,
                                   csr, conv_b + l * 64, ln_g + l * 64, ln_b + l * 64,
                                   hb, N);
  }

  k_pool<<<1024, 256, 0, stream>>>(hb, gsum, N);
  k_head<<<1, 256, 0, stream>>>(gsum, fc1_w, fc1_b, fcn_g, fcn_b, fc2_w, fc2_b, out,
                                1.0f / (float)N);
}

// Round 16
// 498.661 us; speedup vs baseline: 1.0526x; 1.0490x over previous
//
#include <hip/hip_runtime.h>
#include <hip/hip_bf16.h>
#include <math.h>

typedef __attribute__((ext_vector_type(8))) short short8v;
typedef __attribute__((ext_vector_type(4))) float float4v;
typedef __attribute__((ext_vector_type(2))) float floatx2;

// ---------------- wave helpers (wave64) ----------------
__device__ __forceinline__ float wsum(float v) {
#pragma unroll
  for (int s = 32; s > 0; s >>= 1) v += __shfl_xor(v, s, 64);
  return v;
}
__device__ __forceinline__ float bcast(float v, int l) {
  return __int_as_float(__builtin_amdgcn_readlane(__float_as_int(v), l));
}
__device__ __forceinline__ int bcasti(int v, int l) {
  return __builtin_amdgcn_readlane(v, l);
}
__device__ __forceinline__ unsigned bf16bits(float f) {  // round-to-nearest-even
  unsigned u = __float_as_uint(f);
  return (u + 0x7fffu + ((u >> 16) & 1u)) >> 16;
}

// ---------------- embed: hb[n][64] = bf16(leaky0.1(LN(x@W+b)*g+beta)) ------
__global__ void k_embed(const float* __restrict__ x, const float* __restrict__ w,
                        const float* __restrict__ b, const float* __restrict__ g,
                        const float* __restrict__ beta, short* __restrict__ hb, int n) {
  __shared__ float ws[16 * 64];
  for (int i = threadIdx.x; i < 16 * 64; i += blockDim.x) ws[i] = w[i];
  __syncthreads();
  int wid = (blockIdx.x * blockDim.x + threadIdx.x) >> 6;
  int lane = threadIdx.x & 63;
  if (wid >= n) return;
  const float* xr = x + (size_t)wid * 16;
  float acc = b[lane];
#pragma unroll
  for (int k = 0; k < 16; ++k) acc = fmaf(xr[k], ws[k * 64 + lane], acc);
  float mean = wsum(acc) * 0.015625f;
  float xc = acc - mean;
  float var = wsum(xc * xc) * 0.015625f;
  float y = xc * rsqrtf(var + 1e-5f) * g[lane] + beta[lane];
  y = (y >= 0.f) ? y : 0.1f * y;
  hb[(size_t)wid * 64 + lane] = (short)bf16bits(y);
}

// ---------------- CSR build (by dst), self-loops appended virtually --------
__global__ void k_deg(const int* __restrict__ ei, int E, int n, int* __restrict__ deg,
                      int* __restrict__ pos) {
  int i = blockIdx.x * blockDim.x + threadIdx.x;
  int tot = E + n;
  if (i >= tot) return;
  int d = (i < E) ? ei[E + i] : (i - E);
  pos[i] = atomicAdd(&deg[d], 1);
}

__global__ void k_scanA(const int* __restrict__ deg, int n, int* __restrict__ texcl,
                        int* __restrict__ bsum) {
  __shared__ int sh[256];
  int bid = blockIdx.x, tid = threadIdx.x;
  int base = bid * 2048 + tid * 8;
  int s = 0;
#pragma unroll
  for (int i = 0; i < 8; ++i) {
    int idx = base + i;
    s += (idx < n) ? deg[idx] : 0;
  }
  sh[tid] = s;
  __syncthreads();
  for (int st = 1; st < 256; st <<= 1) {
    int t = (tid >= st) ? sh[tid - st] : 0;
    __syncthreads();
    sh[tid] += t;
    __syncthreads();
  }
  texcl[bid * 256 + tid] = sh[tid] - s;
  if (tid == 255) bsum[bid] = sh[255];
}

__global__ void k_scanB(int* __restrict__ bsum, int nb) {
  __shared__ int sh[256];
  int tid = threadIdx.x;
  int v = (tid < nb) ? bsum[tid] : 0;
  sh[tid] = v;
  __syncthreads();
  for (int st = 1; st < 256; st <<= 1) {
    int t = (tid >= st) ? sh[tid - st] : 0;
    __syncthreads();
    sh[tid] += t;
    __syncthreads();
  }
  if (tid < nb) bsum[tid] = sh[tid] - v;  // exclusive
}

__global__ void k_scanC(const int* __restrict__ deg, int n, const int* __restrict__ texcl,
                        const int* __restrict__ bsum, int* __restrict__ off, int total) {
  int bid = blockIdx.x, tid = threadIdx.x;
  int run = bsum[bid] + texcl[bid * 256 + tid];
  int base = bid * 2048 + tid * 8;
#pragma unroll
  for (int i = 0; i < 8; ++i) {
    int idx = base + i;
    if (idx < n) {
      off[idx] = run;
      run += deg[idx];
    }
  }
  if (bid == 0 && tid == 0) off[n] = total;
}

__global__ void k_scatter(const int* __restrict__ ei, int E, int n,
                          const int* __restrict__ off, const int* __restrict__ pos,
                          int* __restrict__ csr) {
  int i = blockIdx.x * blockDim.x + threadIdx.x;
  int tot = E + n;
  if (i >= tot) return;
  int s, d;
  if (i < E) { s = ei[i]; d = ei[E + i]; } else { s = i - E; d = i - E; }
  csr[off[d] + pos[i]] = s;
}

// ---------------- hp = hb @ W via MFMA, fused attention logits -------------
// Grid-strided: W staged to LDS once per block. Messages stored as OCP
// fp8-e4m3 pairs {head0,head1} = 2B per channel (HW cvt_pk_fp8_f32).
__global__ __launch_bounds__(256) void k_hp(
    const short* __restrict__ hb, const float* __restrict__ W,
    const float* __restrict__ asrc, const float* __restrict__ adst,
    unsigned short* __restrict__ hp8, float2* __restrict__ al_s,
    float2* __restrict__ al_d, int n, int ntiles) {
  __shared__ short wlds[16 * 64 * 8];  // 16 KB: [(kh*8+ct)*64 + lane]*8
  int tid = threadIdx.x;
  for (int idx = tid; idx < 1024; idx += 256) {
    int fr = idx >> 6;  // kh = fr>>3, ct = fr&7
    int ls = idx & 63;
    int kb = (fr >> 3) * 32 + (ls >> 4) * 8;
    int c = (fr & 7) * 16 + (ls & 15);
    short tmp[8];
#pragma unroll
    for (int j = 0; j < 8; ++j)
      tmp[j] = (short)bf16bits(W[(size_t)(kb + j) * 128 + c]);
    *reinterpret_cast<short8v*>(&wlds[idx * 8]) = *reinterpret_cast<const short8v*>(tmp);
  }
  __syncthreads();
  int lane = tid & 63;
  int warp = tid >> 6;
  int col = lane & 15, kg = lane >> 4;
  for (int tile = blockIdx.x; tile < ntiles; tile += gridDim.x) {
    int nb = (tile * 4 + warp) * 16;
    if (nb >= n) continue;
    int rowA = nb + col;
    if (rowA > n - 1) rowA = n - 1;  // clamp (safe duplicate read)
    const short8v* aptr =
        reinterpret_cast<const short8v*>(hb + (size_t)rowA * 64 + kg * 8);
    short8v af0 = aptr[0];
    short8v af1 = aptr[4];  // +32 elements (second K-half)
    float ps0[4] = {0, 0, 0, 0}, ps1[4] = {0, 0, 0, 0};
    float pd0[4] = {0, 0, 0, 0}, pd1[4] = {0, 0, 0, 0};
#pragma unroll
    for (int ctp = 0; ctp < 4; ++ctp) {
      const short8v* bp0 =
          reinterpret_cast<const short8v*>(&wlds[((0 * 8 + ctp) * 64 + lane) * 8]);
      const short8v* bp1 =
          reinterpret_cast<const short8v*>(&wlds[((1 * 8 + ctp) * 64 + lane) * 8]);
      float4v accA = {0.f, 0.f, 0.f, 0.f};
      accA = __builtin_amdgcn_mfma_f32_16x16x32_bf16(af0, *bp0, accA, 0, 0, 0);
      accA = __builtin_amdgcn_mfma_f32_16x16x32_bf16(af1, *bp1, accA, 0, 0, 0);
      const short8v* bq0 =
          reinterpret_cast<const short8v*>(&wlds[((0 * 8 + ctp + 4) * 64 + lane) * 8]);
      const short8v* bq1 =
          reinterpret_cast<const short8v*>(&wlds[((1 * 8 + ctp + 4) * 64 + lane) * 8]);
      float4v accB = {0.f, 0.f, 0.f, 0.f};
      accB = __builtin_amdgcn_mfma_f32_16x16x32_bf16(af0, *bq0, accB, 0, 0, 0);
      accB = __builtin_amdgcn_mfma_f32_16x16x32_bf16(af1, *bq1, accB, 0, 0, 0);
      int c = ctp * 16 + col;  // head-local column
      float a_s0 = asrc[c], a_s1 = asrc[64 + c];
      float a_d0 = adst[c], a_d1 = adst[64 + c];
#pragma unroll
      for (int r = 0; r < 4; ++r) {
        int node = nb + kg * 4 + r;
        unsigned pk8 = __builtin_amdgcn_cvt_pk_fp8_f32(accA[r], accB[r], 0, false);
        if (node < n) hp8[(size_t)node * 64 + c] = (unsigned short)pk8;
        ps0[r] = fmaf(accA[r], a_s0, ps0[r]);
        ps1[r] = fmaf(accB[r], a_s1, ps1[r]);
        pd0[r] = fmaf(accA[r], a_d0, pd0[r]);
        pd1[r] = fmaf(accB[r], a_d1, pd1[r]);
      }
    }
#pragma unroll
    for (int m = 1; m < 16; m <<= 1) {
#pragma unroll
      for (int r = 0; r < 4; ++r) {
        ps0[r] += __shfl_xor(ps0[r], m, 64);
        ps1[r] += __shfl_xor(ps1[r], m, 64);
        pd0[r] += __shfl_xor(pd0[r], m, 64);
        pd1[r] += __shfl_xor(pd1[r], m, 64);
      }
    }
    if (col == 0) {
#pragma unroll
      for (int r = 0; r < 4; ++r) {
        int node = nb + kg * 4 + r;
        if (node < n) {
          al_s[node] = make_float2(ps0[r], ps1[r]);
          al_d[node] = make_float2(pd0[r], pd1[r]);
        }
      }
    }
  }
}

// ---------------- GAT aggregate + head-mean + bias + LN + leaky ------------
// fp8 messages: 2B/lane gather = 128B (one cacheline) per edge. Decode via
// HW cvt_pk_f32_fp8 (1 instr -> both heads). Weights/denoms/LN stay fp32.
__global__ void k_gat(const unsigned short* __restrict__ hp8,
                      const float* __restrict__ al_s, const float* __restrict__ al_d,
                      const int* __restrict__ off, const int* __restrict__ csr,
                      const float* __restrict__ bias, const float* __restrict__ g,
                      const float* __restrict__ b, short* __restrict__ hb, int n) {
  int gw = (blockIdx.x * blockDim.x + threadIdx.x) >> 6;
  if (gw >= n) return;
  int node = __builtin_amdgcn_readfirstlane(gw);
  int lane = threadIdx.x & 63;
  const float2* al2 = (const float2*)al_s;
  float2 adv = ((const float2*)al_d)[node];
  int beg = off[node], end = off[node + 1];
  float acc0 = 0.f, acc1 = 0.f, dnl0 = 0.f, dnl1 = 0.f;
  for (int cb = beg; cb < end; cb += 64) {
    int jj = cb + lane;
    int sv = 0;
    float w0v = 0.f, w1v = 0.f;
    if (jj < end) {
      sv = csr[jj];
      float2 e = al2[sv];
      float e0 = e.x + adv.x; e0 = (e0 >= 0.f) ? e0 : 0.2f * e0;
      float e1 = e.y + adv.y; e1 = (e1 >= 0.f) ? e1 : 0.2f * e1;
      w0v = __expf(e0);
      w1v = __expf(e1);
    }
    dnl0 += w0v; dnl1 += w1v;
    int cnt = min(64, end - cb);
    int t = 0;
    for (; t + 8 <= cnt; t += 8) {  // 8 gathers in flight
      unsigned short us[8];
      float w0[8], w1[8];
#pragma unroll
      for (int i = 0; i < 8; ++i) {
        int s = bcasti(sv, t + i);
        w0[i] = bcast(w0v, t + i);
        w1[i] = bcast(w1v, t + i);
        us[i] = hp8[(size_t)s * 64 + lane];
      }
#pragma unroll
      for (int i = 0; i < 8; ++i) {
        floatx2 m = __builtin_amdgcn_cvt_pk_f32_fp8((int)us[i], false);
        acc0 = fmaf(w0[i], m.x, acc0);
        acc1 = fmaf(w1[i], m.y, acc1);
      }
    }
    for (; t < cnt; ++t) {
      int s = bcasti(sv, t);
      float w0 = bcast(w0v, t), w1 = bcast(w1v, t);
      unsigned short us = hp8[(size_t)s * 64 + lane];
      floatx2 m = __builtin_amdgcn_cvt_pk_f32_fp8((int)us, false);
      acc0 = fmaf(w0, m.x, acc0);
      acc1 = fmaf(w1, m.y, acc1);
    }
  }
  float dn0 = wsum(dnl0), dn1 = wsum(dnl1);
  float oc = 0.5f * (acc0 / (dn0 + 1e-16f) + acc1 / (dn1 + 1e-16f)) + bias[lane];
  float mean = wsum(oc) * 0.015625f;
  float xc = oc - mean;
  float var = wsum(xc * xc) * 0.015625f;
  float y = xc * rsqrtf(var + 1e-5f) * g[lane] + b[lane];
  y = (y >= 0.f) ? y : 0.1f * y;
  hb[(size_t)node * 64 + lane] = (short)bf16bits(y);
}

// ---------------- global mean pool (column sums, bf16 input) ---------------
__global__ void k_pool(const short* __restrict__ hb, float* __restrict__ gsum, int n) {
  __shared__ float sh[256];
  int col = threadIdx.x & 63;
  int rw = threadIdx.x >> 6;
  float acc = 0.f;
  for (long r = (long)blockIdx.x * 4 + rw; r < n; r += (long)gridDim.x * 4) {
    unsigned u = (unsigned)(unsigned short)hb[r * 64 + col];
    acc += __uint_as_float(u << 16);
  }
  sh[threadIdx.x] = acc;
  __syncthreads();
  if (threadIdx.x < 64) {
    float s = sh[threadIdx.x] + sh[64 + threadIdx.x] + sh[128 + threadIdx.x] +
              sh[192 + threadIdx.x];
    atomicAdd(&gsum[col], s);
  }
}

// ---------------- head: fc1 -> LN -> leaky -> fc2 -> sigmoid ---------------
__global__ void k_head(const float* __restrict__ gsum, const float* __restrict__ fc1w,
                       const float* __restrict__ fc1b, const float* __restrict__ fng,
                       const float* __restrict__ fnb, const float* __restrict__ fc2w,
                       const float* __restrict__ fc2b, float* __restrict__ out,
                       float invN) {
  __shared__ float t[64];
  __shared__ float gl[64];
  int tid = threadIdx.x;
  if (tid < 64) gl[tid] = gsum[tid] * invN;
  __syncthreads();
  if (tid < 64) {  // wave 0 only
    float z = fc1b[tid];
    for (int k = 0; k < 64; ++k) z = fmaf(gl[k], fc1w[k * 64 + tid], z);
    float mean = wsum(z) * 0.015625f;
    float xc = z - mean;
    float var = wsum(xc * xc) * 0.015625f;
    float y = xc * rsqrtf(var + 1e-5f) * fng[tid] + fnb[tid];
    t[tid] = (y >= 0.f) ? y : 0.1f * y;
  }
  __syncthreads();
  if (tid < 200) {
    float o = fc2b[tid];
    for (int k = 0; k < 64; ++k) o = fmaf(t[k], fc2w[k * 200 + tid], o);
    out[tid] = 1.f / (1.f + expf(-o));
  }
}

// ---------------------------------------------------------------------------
extern "C" void kernel_launch(void* const* d_in, const int* in_sizes, int n_in,
                              void* d_out, int out_size, void* d_ws, size_t ws_size,
                              hipStream_t stream) {
  const float* x      = (const float*)d_in[0];
  const int*   ei     = (const int*)d_in[1];
  const float* emb_w  = (const float*)d_in[2];
  const float* emb_b  = (const float*)d_in[3];
  const float* emb_g  = (const float*)d_in[4];
  const float* emb_be = (const float*)d_in[5];
  const float* lin_w  = (const float*)d_in[6];
  const float* att_s  = (const float*)d_in[7];
  const float* att_d  = (const float*)d_in[8];
  const float* conv_b = (const float*)d_in[9];
  const float* ln_g   = (const float*)d_in[10];
  const float* ln_b   = (const float*)d_in[11];
  const float* fc1_w  = (const float*)d_in[12];
  const float* fc1_b  = (const float*)d_in[13];
  const float* fcn_g  = (const float*)d_in[14];
  const float* fcn_b  = (const float*)d_in[15];
  const float* fc2_w  = (const float*)d_in[16];
  const float* fc2_b  = (const float*)d_in[17];
  float* out = (float*)d_out;

  int N = in_sizes[0] / 16;
  int E = in_sizes[1] / 2;
  int tot = E + N;
  int nb_scan = (N + 2047) / 2048;  // 49 for N=100k (<=256 required)

  char* p = (char*)d_ws;
  auto alloc = [&](size_t bytes) {
    char* r = p;
    p += (bytes + 255) & ~(size_t)255;
    return r;
  };
  short*          hb    = (short*)alloc((size_t)N * 64 * 2);
  unsigned short* hp8   = (unsigned short*)alloc((size_t)N * 64 * 2);
  float2*         al_s  = (float2*)alloc((size_t)N * 8);
  float2*         al_d  = (float2*)alloc((size_t)N * 8);
  int*            deg   = (int*)alloc((size_t)N * 4);
  int*            off   = (int*)alloc((size_t)(N + 1) * 4);
  int*            pos   = (int*)alloc((size_t)tot * 4);
  int*            csr   = (int*)alloc((size_t)tot * 4);
  float*          gsum  = (float*)alloc(64 * 4);
  int*            texcl = (int*)alloc((size_t)nb_scan * 256 * 4);
  int*            bsum  = (int*)alloc((size_t)nb_scan * 4);

  hipMemsetAsync(deg, 0, (size_t)N * 4, stream);
  hipMemsetAsync(gsum, 0, 64 * 4, stream);

  int eb = (tot + 255) / 256;
  k_deg<<<eb, 256, 0, stream>>>(ei, E, N, deg, pos);
  k_scanA<<<nb_scan, 256, 0, stream>>>(deg, N, texcl, bsum);
  k_scanB<<<1, 256, 0, stream>>>(bsum, nb_scan);
  k_scanC<<<nb_scan, 256, 0, stream>>>(deg, N, texcl, bsum, off, tot);
  k_scatter<<<eb, 256, 0, stream>>>(ei, E, N, off, pos, csr);

  int nbe = (N + 3) / 4;  // one wave per node, 4 waves/block
  k_embed<<<nbe, 256, 0, stream>>>(x, emb_w, emb_b, emb_g, emb_be, hb, N);

  int ntiles = (N + 63) / 64;                 // 64 nodes per tile
  int nbh = ntiles < 512 ? ntiles : 512;      // grid-stride, W staged once/block
  for (int l = 0; l < 3; ++l) {
    k_hp<<<nbh, 256, 0, stream>>>(hb, lin_w + (size_t)l * 64 * 128, att_s + l * 128,
                                  att_d + l * 128, hp8, al_s, al_d, N, ntiles);
    k_gat<<<nbe, 256, 0, stream>>>(hp8, (const float*)al_s, (const float*)al_d, off,
                                   csr, conv_b + l * 64, ln_g + l * 64, ln_b + l * 64,
                                   hb, N);
  }

  k_pool<<<1024, 256, 0, stream>>>(hb, gsum, N);
  k_head<<<1, 256, 0, stream>>>(gsum, fc1_w, fc1_b, fcn_g, fcn_b, fc2_w, fc2_b, out,
                                1.0f / (float)N);
}